// Round 1
// baseline (1341.249 us; speedup 1.0000x reference)
//
#include <hip/hip_runtime.h>
#include <math.h>

#define LEAKY 0.2f
#define HDIM 64

// ws layout (floats): [0, 3N) agg, [3N, 4N) cnt, [4N, 4N+8) consts
//   consts[0] = C_edge (collapsed edge-MLP linear coefficient)
//   consts[1] = flag: any bp1[k] != 0  (forces general slow path)

__global__ void precompute_kernel(const float* __restrict__ Wp1,
                                  const float* __restrict__ bp1,
                                  const float* __restrict__ Wp2,
                                  float* __restrict__ consts) {
    int k = threadIdx.x;  // launched with 64 threads == HDIM == one wave
    float w1 = Wp1[k];
    float slope = (w1 >= 0.f) ? 1.f : LEAKY;
    float c = Wp2[k] * w1 * slope;
    float bnz = (bp1[k] != 0.f) ? 1.f : 0.f;
    #pragma unroll
    for (int off = 32; off > 0; off >>= 1) {
        c += __shfl_down(c, off, 64);
        bnz += __shfl_down(bnz, off, 64);
    }
    if (k == 0) { consts[0] = c; consts[1] = bnz; }
}

__global__ void edge_kernel(const float* __restrict__ x, const int* __restrict__ ei,
                            const float* __restrict__ Wp1, const float* __restrict__ bp1,
                            const float* __restrict__ Wp2,
                            const float* __restrict__ consts,
                            float* __restrict__ agg, float* __restrict__ cnt,
                            int E) {
    __shared__ float sW1[HDIM], sb1[HDIM], sW2[HDIM];
    const float C = consts[0];
    const bool slow = (consts[1] != 0.f);
    if (slow) {
        for (int k = threadIdx.x; k < HDIM; k += blockDim.x) {
            sW1[k] = Wp1[k]; sb1[k] = bp1[k]; sW2[k] = Wp2[k];
        }
        __syncthreads();
    }
    int e = blockIdx.x * blockDim.x + threadIdx.x;
    if (e >= E) return;
    int r = ei[e];
    int c = ei[E + e];
    float dx = x[3*r]     - x[3*c];
    float dy = x[3*r + 1] - x[3*c + 1];
    float dz = x[3*r + 2] - x[3*c + 2];
    float rad = sqrtf(dx*dx + dy*dy + dz*dz);
    float eo;
    if (!slow) {
        // bp1 == 0 and rad >= 0: leaky_relu(rad*Wp1[k]) = rad*Wp1[k]*slope_k,
        // so the whole MLP is tanh(C * rad).
        eo = tanhf(C * rad);
    } else {
        float acc = 0.f;
        #pragma unroll
        for (int k = 0; k < HDIM; k++) {
            float h = fmaf(rad, sW1[k], sb1[k]);
            h = (h > 0.f) ? h : LEAKY * h;
            acc = fmaf(sW2[k], h, acc);
        }
        eo = tanhf(acc);
    }
    atomicAdd(&agg[3*r],     dx * eo);
    atomicAdd(&agg[3*r + 1], dy * eo);
    atomicAdd(&agg[3*r + 2], dz * eo);
    atomicAdd(&cnt[r], 1.0f);
}

__global__ void node_kernel(const float* __restrict__ x, const float* __restrict__ vel_norm,
                            const float* __restrict__ vel,
                            const float* __restrict__ W1, const float* __restrict__ b1,
                            const float* __restrict__ W2, const float* __restrict__ b2,
                            const float* __restrict__ agg, const float* __restrict__ cnt,
                            float* __restrict__ out, int N) {
    __shared__ float sW1[HDIM], sb1[HDIM], sW2[HDIM];
    for (int k = threadIdx.x; k < HDIM; k += blockDim.x) {
        sW1[k] = W1[k]; sb1[k] = b1[k]; sW2[k] = W2[k];
    }
    __syncthreads();
    int i = blockIdx.x * blockDim.x + threadIdx.x;
    if (i >= N) return;
    float vn = vel_norm[i];
    float acc = b2[0];
    #pragma unroll
    for (int k = 0; k < HDIM; k++) {
        float h = fmaf(vn, sW1[k], sb1[k]);
        h = (h > 0.f) ? h : LEAKY * h;
        acc = fmaf(sW2[k], h, acc);
    }
    float inv = 1.0f / fmaxf(cnt[i], 1.0f);
    #pragma unroll
    for (int d = 0; d < 3; d++) {
        out[3*i + d] = x[3*i + d] + agg[3*i + d] * inv + vel[3*i + d] * acc;
    }
}

extern "C" void kernel_launch(void* const* d_in, const int* in_sizes, int n_in,
                              void* d_out, int out_size, void* d_ws, size_t ws_size,
                              hipStream_t stream) {
    const float* x        = (const float*)d_in[0];
    const float* vel_norm = (const float*)d_in[1];
    const float* vel      = (const float*)d_in[2];
    const int*   ei       = (const int*)  d_in[3];
    const float* W1       = (const float*)d_in[4];
    const float* b1       = (const float*)d_in[5];
    const float* W2       = (const float*)d_in[6];
    const float* b2       = (const float*)d_in[7];
    const float* Wp1      = (const float*)d_in[8];
    const float* bp1      = (const float*)d_in[9];
    const float* Wp2      = (const float*)d_in[10];

    const int N = in_sizes[0] / 3;
    const int E = in_sizes[3] / 2;

    float* ws     = (float*)d_ws;
    float* agg    = ws;                       // 3N floats
    float* cnt    = ws + 3 * (size_t)N;       // N floats
    float* consts = ws + 4 * (size_t)N;       // 8 floats

    // zero accumulators + consts (ws is re-poisoned to 0xAA before every launch)
    hipMemsetAsync(d_ws, 0, (4 * (size_t)N + 8) * sizeof(float), stream);

    precompute_kernel<<<1, 64, 0, stream>>>(Wp1, bp1, Wp2, consts);
    edge_kernel<<<(E + 255) / 256, 256, 0, stream>>>(x, ei, Wp1, bp1, Wp2, consts,
                                                     agg, cnt, E);
    node_kernel<<<(N + 255) / 256, 256, 0, stream>>>(x, vel_norm, vel, W1, b1, W2, b2,
                                                     agg, cnt, (float*)d_out, N);
}